// Round 2
// baseline (456.271 us; speedup 1.0000x reference)
//
#include <hip/hip_runtime.h>

#define BLOCK 256
#define NB 5      // objects per scene
#define DD 12     // per-object feature dim
#define EE 64     // goal embedding dim
#define HH 32     // F1 hidden dim
#define ROW 81    // D + E + N
#define OUTW 405  // N * ROW

__global__ __launch_bounds__(BLOCK, 3) void fused_relnet_kernel(
    const float* __restrict__ obs, const float* __restrict__ ghat,
    const float* __restrict__ W1, const float* __restrict__ b1,
    const float* __restrict__ W2, const float* __restrict__ b2,
    float* __restrict__ out, int B)
{
    __shared__ float s_w2s[HH];     // rowsum(W2)
    __shared__ float s_sb2;         // sum(b2)
    __shared__ float s_zhat[BLOCK * NB];

    const int tid = threadIdx.x;

    // ---- batch-independent scalars, computed cooperatively ----
    if (tid < HH) {
        float s = 0.f;
        #pragma unroll
        for (int e = 0; e < EE; ++e) s += W2[tid * EE + e];
        s_w2s[tid] = s;
    } else if (tid == HH) {
        float s = 0.f;
        #pragma unroll
        for (int e = 0; e < EE; ++e) s += b2[e];
        s_sb2 = s;
    }
    __syncthreads();

    const int i = blockIdx.x * BLOCK + tid;   // batch index

    if (i < B) {
        // ---- obs row (60 floats) in registers; ghat streamed per chunk ----
        float o[NB * DD];
        {
            const float4* p = reinterpret_cast<const float4*>(obs + (size_t)i * (NB * DD));
            #pragma unroll
            for (int q = 0; q < NB * DD / 4; ++q) {
                float4 v = p[q];
                o[4*q+0] = v.x; o[4*q+1] = v.y; o[4*q+2] = v.z; o[4*q+3] = v.w;
            }
        }

        float w[NB * NB];    // attention logits (b2.ghat term is softmax-invariant: dropped)
        float hw[NB * NB];   // h . rowsum(W2)
        #pragma unroll
        for (int q = 0; q < NB * NB; ++q) { w[q] = 0.f; hw[q] = 0.f; }

        const float* grow = ghat + (size_t)i * EE;

        // ---- hidden units in chunks of 8 (outer loop NOT unrolled) ----
        for (int c = 0; c < HH / 8; ++c) {
            const int h0 = c * 8;
            // g2[hp] = W2[h0+hp] . ghat[i]  -- stream ghat 16 floats at a time
            float g2[8];
            #pragma unroll
            for (int hp = 0; hp < 8; ++hp) g2[hp] = 0.f;
            #pragma unroll
            for (int e0 = 0; e0 < EE; e0 += 16) {
                float gc[16];
                const float4* gp = reinterpret_cast<const float4*>(grow + e0);
                #pragma unroll
                for (int q = 0; q < 4; ++q) {
                    float4 v = gp[q];
                    gc[4*q+0] = v.x; gc[4*q+1] = v.y; gc[4*q+2] = v.z; gc[4*q+3] = v.w;
                }
                #pragma unroll
                for (int hp = 0; hp < 8; ++hp) {
                    #pragma unroll
                    for (int q = 0; q < 16; ++q)
                        g2[hp] += W2[(h0 + hp) * EE + e0 + q] * gc[q];
                }
            }
            // pair contributions for these 8 hidden units
            #pragma unroll
            for (int hp = 0; hp < 8; ++hp) {
                const int h = h0 + hp;
                const float w2s = s_w2s[h];
                float a[NB], bb[NB];
                #pragma unroll
                for (int j = 0; j < NB; ++j) {
                    float acc = b1[h];
                    float accb = 0.f;
                    #pragma unroll
                    for (int d = 0; d < DD; ++d) {
                        acc  += o[j*DD + d] * W1[d*HH + h];
                        accb += o[j*DD + d] * W1[(DD + d)*HH + h];
                    }
                    a[j] = acc; bb[j] = accb;
                }
                #pragma unroll
                for (int j = 0; j < NB; ++j) {
                    #pragma unroll
                    for (int k = 0; k < NB; ++k) {
                        float hv = fmaxf(a[j] + bb[k], 0.f);
                        w[j*NB + k]  += hv * g2[hp];
                        hw[j*NB + k] += hv * w2s;
                    }
                }
            }
        }

        // ---- softmax over 25 pairs + zhat ----
        float m = w[0];
        #pragma unroll
        for (int q = 1; q < NB * NB; ++q) m = fmaxf(m, w[q]);
        float l = 0.f;
        float zacc[NB], racc[NB];
        #pragma unroll
        for (int j = 0; j < NB; ++j) { zacc[j] = 0.f; racc[j] = 0.f; }
        #pragma unroll
        for (int j = 0; j < NB; ++j) {
            #pragma unroll
            for (int k = 0; k < NB; ++k) {
                float e = __expf(w[j*NB + k] - m);
                l += e;
                zacc[j] += e * hw[j*NB + k];
                racc[j] += e;
            }
        }
        const float sb2 = s_sb2;
        const float invl = 1.f / l;
        #pragma unroll
        for (int j = 0; j < NB; ++j)
            s_zhat[tid * NB + j] = (zacc[j] + sb2 * racc[j]) * invl;
    }

    __syncthreads();

    // ---- phase 2: wave-structured coalesced output write ----
    // Each wave emits one batch row per iteration:
    //   - 64-lane contiguous ghat store x5 rows
    //   - masked obs store (lanes 0..59), masked zhat store (lanes 0..24)
    const int wave = tid >> 6;
    const int lane = tid & 63;
    const int jo  = lane / DD,  doo = lane - jo * DD;    // obs slot for this lane
    const int jz  = lane / NB,  kz  = lane - jz * NB;    // zhat slot for this lane
    const int bb0 = blockIdx.x * BLOCK;

    for (int il = wave; il < BLOCK; il += 4) {
        const int ib = bb0 + il;
        if (ib >= B) break;
        float* orow = out + (size_t)ib * OUTW;
        const float gv = ghat[(size_t)ib * EE + lane];
        #pragma unroll
        for (int j = 0; j < NB; ++j)
            orow[j * ROW + DD + lane] = gv;
        if (lane < NB * DD) {
            const float ov = obs[(size_t)ib * (NB * DD) + lane];
            orow[jo * ROW + doo] = ov;
        }
        if (lane < NB * NB) {
            orow[jz * ROW + DD + EE + kz] = s_zhat[il * NB + kz];
        }
    }
}

extern "C" void kernel_launch(void* const* d_in, const int* in_sizes, int n_in,
                              void* d_out, int out_size, void* d_ws, size_t ws_size,
                              hipStream_t stream) {
    const float* obs  = (const float*)d_in[0];
    const float* ghat = (const float*)d_in[1];
    const float* W1   = (const float*)d_in[2];
    const float* b1   = (const float*)d_in[3];
    const float* W2   = (const float*)d_in[4];
    const float* b2   = (const float*)d_in[5];
    float* out = (float*)d_out;

    const int B = in_sizes[0] / (NB * DD);
    const int grid = (B + BLOCK - 1) / BLOCK;
    hipLaunchKernelGGL(fused_relnet_kernel, dim3(grid), dim3(BLOCK), 0, stream,
                       obs, ghat, W1, b1, W2, b2, out, B);
}

// Round 3
// 146.545 us; speedup vs baseline: 3.1135x; 3.1135x over previous
//
#include <hip/hip_runtime.h>

#define BLOCK 256
#define NB 5      // objects per scene
#define DD 12     // per-object feature dim
#define EE 64     // goal embedding dim
#define HH 32     // F1 hidden dim
#define ROW 81    // D + E + N
#define OUTW 405  // N * ROW
#define TILE 64   // batch rows per block in assemble kernel

// ---------------- kernel A: compute zhat[B,5] ----------------
__global__ __launch_bounds__(BLOCK) void zhat_kernel(
    const float* __restrict__ obs, const float* __restrict__ ghat,
    const float* __restrict__ W1, const float* __restrict__ b1,
    const float* __restrict__ W2, const float* __restrict__ b2,
    float* __restrict__ zbuf, int zstride, int zoff, int B)
{
    __shared__ float s_w2s[HH];          // rowsum(W2)
    __shared__ float s_sb2;              // sum(b2)
    __shared__ float s_g2[BLOCK * 33];   // per-thread W2@ghat (stride 33: conflict-free)

    const int tid = threadIdx.x;

    if (tid < HH) {
        float s = 0.f;
        #pragma unroll
        for (int e = 0; e < EE; ++e) s += W2[tid * EE + e];
        s_w2s[tid] = s;
    } else if (tid == HH) {
        float s = 0.f;
        #pragma unroll
        for (int e = 0; e < EE; ++e) s += b2[e];
        s_sb2 = s;
    }

    const int i = blockIdx.x * BLOCK + tid;   // batch index

    // ---- GEMV g2 = W2 @ ghat_i ; ghat read exactly once ----
    float g2[HH];
    #pragma unroll
    for (int h = 0; h < HH; ++h) g2[h] = 0.f;
    if (i < B) {
        const float* grow = ghat + (size_t)i * EE;
        #pragma unroll
        for (int e0 = 0; e0 < EE; e0 += 16) {
            float gc[16];
            const float4* gp = reinterpret_cast<const float4*>(grow + e0);
            #pragma unroll
            for (int q = 0; q < 4; ++q) {
                float4 v = gp[q];
                gc[4*q+0] = v.x; gc[4*q+1] = v.y; gc[4*q+2] = v.z; gc[4*q+3] = v.w;
            }
            #pragma unroll
            for (int h = 0; h < HH; ++h) {
                #pragma unroll
                for (int q = 0; q < 16; ++q)
                    g2[h] += W2[h * EE + e0 + q] * gc[q];
            }
        }
    }
    // park g2 in LDS so the (non-unrolled) chunk loop can runtime-index it
    #pragma unroll
    for (int h = 0; h < HH; ++h) s_g2[tid * 33 + h] = g2[h];
    __syncthreads();   // also publishes s_w2s / s_sb2

    if (i < B) {
        // ---- obs row (60 floats) in registers ----
        float o[NB * DD];
        {
            const float4* p = reinterpret_cast<const float4*>(obs + (size_t)i * (NB * DD));
            #pragma unroll
            for (int q = 0; q < NB * DD / 4; ++q) {
                float4 v = p[q];
                o[4*q+0] = v.x; o[4*q+1] = v.y; o[4*q+2] = v.z; o[4*q+3] = v.w;
            }
        }

        float w[NB * NB];    // logits (b2.ghat term softmax-invariant: dropped)
        float hw[NB * NB];   // h . rowsum(W2)
        #pragma unroll
        for (int q = 0; q < NB * NB; ++q) { w[q] = 0.f; hw[q] = 0.f; }

        // ---- hidden units in chunks of 8 (outer loop NOT unrolled) ----
        for (int c = 0; c < HH / 8; ++c) {
            float g2c[8], w2c[8];
            #pragma unroll
            for (int hp = 0; hp < 8; ++hp) {
                g2c[hp] = s_g2[tid * 33 + c * 8 + hp];
                w2c[hp] = s_w2s[c * 8 + hp];
            }
            #pragma unroll
            for (int hp = 0; hp < 8; ++hp) {
                const int h = c * 8 + hp;          // wave-uniform -> scalar loads for W1/b1
                float a[NB], bb[NB];
                #pragma unroll
                for (int j = 0; j < NB; ++j) {
                    float acc = b1[h];
                    float accb = 0.f;
                    #pragma unroll
                    for (int d = 0; d < DD; ++d) {
                        acc  += o[j*DD + d] * W1[d*HH + h];
                        accb += o[j*DD + d] * W1[(DD + d)*HH + h];
                    }
                    a[j] = acc; bb[j] = accb;
                }
                #pragma unroll
                for (int j = 0; j < NB; ++j) {
                    #pragma unroll
                    for (int k = 0; k < NB; ++k) {
                        float hv = fmaxf(a[j] + bb[k], 0.f);
                        w[j*NB + k]  += hv * g2c[hp];
                        hw[j*NB + k] += hv * w2c[hp];
                    }
                }
            }
        }

        // ---- softmax over 25 pairs + zhat ----
        float m = w[0];
        #pragma unroll
        for (int q = 1; q < NB * NB; ++q) m = fmaxf(m, w[q]);
        float l = 0.f;
        float zacc[NB], racc[NB];
        #pragma unroll
        for (int j = 0; j < NB; ++j) { zacc[j] = 0.f; racc[j] = 0.f; }
        #pragma unroll
        for (int j = 0; j < NB; ++j) {
            #pragma unroll
            for (int k = 0; k < NB; ++k) {
                float e = __expf(w[j*NB + k] - m);
                l += e;
                zacc[j] += e * hw[j*NB + k];
                racc[j] += e;
            }
        }
        const float invl = 1.f / l;
        const float sb2 = s_sb2;
        float* zr = zbuf + (size_t)i * zstride + zoff;
        #pragma unroll
        for (int j = 0; j < NB; ++j)
            zr[j] = (zacc[j] + sb2 * racc[j]) * invl;
    }
}

// ---------------- kernel B: assemble output (dense sequential stores) ----------------
__global__ __launch_bounds__(BLOCK) void assemble_kernel(
    const float* __restrict__ obs, const float* __restrict__ ghat,
    const float* __restrict__ zbuf, int zstride, int zoff,
    float* __restrict__ out, int B)
{
    __shared__ float s_obs[TILE * NB * DD];  // 3840 floats
    __shared__ float s_gh[TILE * EE];        // 4096 floats
    __shared__ float s_zh[TILE * NB];        // 320 floats

    const int tid = threadIdx.x;
    const int r0 = blockIdx.x * TILE;
    const int rows = (B - r0 < TILE) ? (B - r0) : TILE;

    for (int t = tid; t < rows * NB * DD; t += BLOCK)
        s_obs[t] = obs[(size_t)r0 * NB * DD + t];
    for (int t = tid; t < rows * EE; t += BLOCK)
        s_gh[t] = ghat[(size_t)r0 * EE + t];
    for (int t = tid; t < rows * NB; t += BLOCK) {
        const int row = t / NB, k = t - row * NB;
        s_zh[t] = zbuf[(size_t)(r0 + row) * zstride + zoff + k];
    }
    __syncthreads();

    const size_t base = (size_t)r0 * OUTW;
    for (int t = tid; t < rows * OUTW; t += BLOCK) {
        const int il = t / OUTW;
        const int r  = t - il * OUTW;
        const int j  = r / ROW;
        const int rr = r - j * ROW;
        float v;
        if (rr < DD)           v = s_obs[il * NB * DD + j * DD + rr];
        else if (rr < DD + EE) v = s_gh[il * EE + (rr - DD)];
        else                   v = s_zh[il * NB + (rr - (DD + EE))];
        out[base + t] = v;
    }
}

extern "C" void kernel_launch(void* const* d_in, const int* in_sizes, int n_in,
                              void* d_out, int out_size, void* d_ws, size_t ws_size,
                              hipStream_t stream) {
    const float* obs  = (const float*)d_in[0];
    const float* ghat = (const float*)d_in[1];
    const float* W1   = (const float*)d_in[2];
    const float* b1   = (const float*)d_in[3];
    const float* W2   = (const float*)d_in[4];
    const float* b2   = (const float*)d_in[5];
    float* out = (float*)d_out;

    const int B = in_sizes[0] / (NB * DD);

    // zhat scratch: d_ws if large enough, else stash in last 5 floats of each
    // output row (kernel B reads its tile's stash before overwriting it).
    float* zbuf; int zstride, zoff;
    if (ws_size >= (size_t)B * NB * sizeof(float)) {
        zbuf = (float*)d_ws; zstride = NB;   zoff = 0;
    } else {
        zbuf = out;          zstride = OUTW; zoff = OUTW - NB;
    }

    const int gridA = (B + BLOCK - 1) / BLOCK;
    hipLaunchKernelGGL(zhat_kernel, dim3(gridA), dim3(BLOCK), 0, stream,
                       obs, ghat, W1, b1, W2, b2, zbuf, zstride, zoff, B);

    const int gridB = (B + TILE - 1) / TILE;
    hipLaunchKernelGGL(assemble_kernel, dim3(gridB), dim3(BLOCK), 0, stream,
                       obs, ghat, zbuf, zstride, zoff, out, B);
}